// Round 19
// baseline (54.751 us; speedup 1.0000x reference)
//
#include <hip/hip_runtime.h>

#define BATCHES 4
#define NPTS    8192
#define INF32   3.0e38f

typedef _Float16 f16x8  __attribute__((ext_vector_type(8)));
typedef float    f32x16 __attribute__((ext_vector_type(16)));

// ---------------- prep: pack A-format (x) and B-format (y) vectors --------
// A-vec (pt u):  [uh0..2, ul0..2, uh0..2, qh, ql, 1, 1, 0,0,0]
// B-vec (pt v):  [-2vh0..2, -2vh0..2, -2vl0..2, 1, 1, sh, sl, 0,0,0]
// dot(Avec(u), Bvec(v)) = |u|^2 + |v|^2 - 2*(uh.vh + ul.vh + uh.vl)  (err ~1e-5)
__device__ inline void fsplit(float v, _Float16& h, _Float16& l) {
    h = (_Float16)v;
    l = (_Float16)(v - (float)h);
}

__global__ __launch_bounds__(256) void chamfer_prep(
    const float* __restrict__ x, const float* __restrict__ y,
    _Float16* __restrict__ pA, _Float16* __restrict__ pB,
    int* __restrict__ mininit /* 65536 ints */)
{
    int i = blockIdx.x * 256 + threadIdx.x;     // point id 0..32767
    mininit[i]         = 0x7F7F7F7F;
    mininit[i + 32768] = 0x7F7F7F7F;

    {   // A-format from x
        const float* xp = x + (size_t)i * 3;
        float p0 = xp[0], p1 = xp[1], p2 = xp[2];
        _Float16 h[3], l[3];
        fsplit(p0, h[0], l[0]); fsplit(p1, h[1], l[1]); fsplit(p2, h[2], l[2]);
        float q = fmaf(p2, p2, fmaf(p1, p1, p0 * p0));
        _Float16 qh, ql; fsplit(q, qh, ql);
        __align__(16) _Float16 av[16];
        #pragma unroll
        for (int k = 0; k < 3; ++k) { av[k] = h[k]; av[3+k] = l[k]; av[6+k] = h[k]; }
        av[9] = qh; av[10] = ql; av[11] = (_Float16)1.0f; av[12] = (_Float16)1.0f;
        av[13] = av[14] = av[15] = (_Float16)0.0f;
        int4* dA = (int4*)(pA + (size_t)i * 16);
        dA[0] = ((int4*)av)[0]; dA[1] = ((int4*)av)[1];
    }
    {   // B-format from y
        const float* yp = y + (size_t)i * 3;
        float p0 = yp[0], p1 = yp[1], p2 = yp[2];
        _Float16 h[3], l[3];
        fsplit(p0, h[0], l[0]); fsplit(p1, h[1], l[1]); fsplit(p2, h[2], l[2]);
        float s = fmaf(p2, p2, fmaf(p1, p1, p0 * p0));
        _Float16 sh, sl; fsplit(s, sh, sl);
        __align__(16) _Float16 bv[16];
        #pragma unroll
        for (int k = 0; k < 3; ++k) {
            bv[k]     = (_Float16)(-2.0f * (float)h[k]);
            bv[3 + k] = bv[k];
            bv[6 + k] = (_Float16)(-2.0f * (float)l[k]);
        }
        bv[9] = (_Float16)1.0f; bv[10] = (_Float16)1.0f; bv[11] = sh; bv[12] = sl;
        bv[13] = bv[14] = bv[15] = (_Float16)0.0f;
        int4* dB = (int4*)(pB + (size_t)i * 16);
        dB[0] = ((int4*)bv)[0]; dB[1] = ((int4*)bv)[1];
    }
}

// ---------------- main: SINGLE GEMM, both mins per tile, E/O pipeline ------
// grid 1024 = batch(4) x rowstrip(64: 128 rows) x colchunk(4: 2048 cols)
// (exactly one resident generation: 4 blocks/CU at 4 waves/SIMD)
// 256 thr = 4 waves; wave owns ONE 32-row A-tile, loops 64 col-tiles as 32
// pairs with R15's proven E/O acc double-buffer. HALF the MFMAs of the dual
// GEMM: rowmin AND colmin extracted from each d^2 tile.
//   rowmin: MIN3X16 into rmin[16] (R15 path).
//   colmin: 7-op min3 tree over the lane's 16 rows + shfl_xor(32) +
//           ONE unique ds_write into per-wave LDS slice cmin[wv][2048]
//           (no LDS atomics -- R8's mistake). Block-merge + global atomicMin.
// A-frag: lane(row=l&31, k=(l>>5)*8+i); B-frag: lane(col=l&31, same k).
// D: col=l&31, row=(reg&3)+8*(reg>>2)+4*(l>>5)  [m74/m101].
__global__ __launch_bounds__(256, 4) void chamfer_mfma(
    const _Float16* __restrict__ pA, const _Float16* __restrict__ pB,
    float* __restrict__ minall /* [0:32768)=x-mins (rows), [32768:65536)=y-mins */)
{
    int bid      = blockIdx.x;
    int b        = bid >> 8;
    int rowstrip = (bid >> 2) & 63;    // 128 rows per block
    int colchunk = bid & 3;            // 2048 cols per block (64 tiles)
    int tid      = threadIdx.x;
    int wv       = tid >> 6, lane = tid & 63;
    int lo       = lane & 31, hi = lane >> 5;

    const _Float16* Adata = pA + (size_t)b * NPTS * 16;
    const _Float16* Bdata = pB + (size_t)b * NPTS * 16;
    float* rowMin = minall + (size_t)b * NPTS;
    float* colMin = minall + 32768 + (size_t)b * NPTS;

    int rw = rowstrip * 128 + wv * 32;   // wave's 32-row A-tile
    int c0 = colchunk * 2048;            // block's col base (64 tiles of 32)

    __shared__ float cmin[4][2048];      // 32 KB; per-wave unique writes

    f16x8 af = *(const f16x8*)(Adata + ((size_t)(rw + lo) << 4) + (hi << 3));

    float rmin[16];
    #pragma unroll
    for (int r = 0; r < 16; ++r) rmin[r] = INF32;

    const f32x16 zero = {0.f,0.f,0.f,0.f,0.f,0.f,0.f,0.f,
                         0.f,0.f,0.f,0.f,0.f,0.f,0.f,0.f};

    auto loadB = [&](int t) -> f16x8 {   // t = col-tile 0..63
        return *(const f16x8*)(Bdata + ((size_t)(c0 + (t << 5) + lo) << 4) + (hi << 3));
    };

    float* cbase = &cmin[wv][lo];        // wave's slice, lane's col slot

#define MIN3X16(P0, P1)                                                \
    _Pragma("unroll")                                                  \
    for (int r = 0; r < 16; ++r)                                       \
        rmin[r] = fminf(fminf(P0[r], P1[r]), rmin[r]);   /* v_min3 */

#define COLFOLD(P, T)                                                  \
    {                                                                  \
        float m0 = fminf(fminf(P[0],  P[1]),  P[2]);                   \
        float m1 = fminf(fminf(P[3],  P[4]),  P[5]);                   \
        float m2 = fminf(fminf(P[6],  P[7]),  P[8]);                   \
        float m3 = fminf(fminf(P[9],  P[10]), P[11]);                  \
        float m4 = fminf(fminf(P[12], P[13]), P[14]);                  \
        float m5 = fminf(fminf(m0, m1), P[15]);                        \
        float m6 = fminf(fminf(m2, m3), m4);                           \
        float cv = fminf(m5, m6);                                      \
        cv = fminf(cv, __shfl_xor(cv, 32, 64));                        \
        cv = fmaxf(cv, 0.f);                                           \
        if (hi == 0) cbase[(T) << 5] = cv;                             \
    }

    // prologue: pair0 (tiles 0,1) in flight; pair1 (tiles 2,3) frags loaded
    f16x8 bcA0 = loadB(0), bcA1 = loadB(1);
    f32x16 accA0 = __builtin_amdgcn_mfma_f32_32x32x16_f16(af, bcA0, zero, 0, 0, 0);
    f32x16 accA1 = __builtin_amdgcn_mfma_f32_32x32x16_f16(af, bcA1, zero, 0, 0, 0);
    f16x8 bcB0 = loadB(2), bcB1 = loadB(3);
    f32x16 accB0, accB1;

    // iter q: consume pair 2q (tiles 4q,4q+1) and pair 2q+1 (tiles 4q+2,4q+3)
    #pragma unroll 1
    for (int q = 0; q < 15; ++q) {
        accB0 = __builtin_amdgcn_mfma_f32_32x32x16_f16(af, bcB0, zero, 0, 0, 0);
        accB1 = __builtin_amdgcn_mfma_f32_32x32x16_f16(af, bcB1, zero, 0, 0, 0);
        bcA0 = loadB(4 * q + 4); bcA1 = loadB(4 * q + 5);
        MIN3X16(accA0, accA1)
        COLFOLD(accA0, 4 * q)
        COLFOLD(accA1, 4 * q + 1)
        accA0 = __builtin_amdgcn_mfma_f32_32x32x16_f16(af, bcA0, zero, 0, 0, 0);
        accA1 = __builtin_amdgcn_mfma_f32_32x32x16_f16(af, bcA1, zero, 0, 0, 0);
        bcB0 = loadB(4 * q + 6); bcB1 = loadB(4 * q + 7);
        MIN3X16(accB0, accB1)
        COLFOLD(accB0, 4 * q + 2)
        COLFOLD(accB1, 4 * q + 3)
    }
    // epilogue: pair 30 (tiles 60,61), pair 31 (tiles 62,63)
    accB0 = __builtin_amdgcn_mfma_f32_32x32x16_f16(af, bcB0, zero, 0, 0, 0);
    accB1 = __builtin_amdgcn_mfma_f32_32x32x16_f16(af, bcB1, zero, 0, 0, 0);
    MIN3X16(accA0, accA1)
    COLFOLD(accA0, 60)
    COLFOLD(accA1, 61)
    MIN3X16(accB0, accB1)
    COLFOLD(accB0, 62)
    COLFOLD(accB1, 63)
#undef MIN3X16
#undef COLFOLD

    // rowmin: fold across the 32 col positions (lane bits 0-4), atomicMin
    #pragma unroll
    for (int r = 0; r < 16; ++r) {
        float v = rmin[r];
        v = fminf(v, __shfl_xor(v, 1, 64));
        v = fminf(v, __shfl_xor(v, 2, 64));
        v = fminf(v, __shfl_xor(v, 4, 64));
        v = fminf(v, __shfl_xor(v, 8, 64));
        v = fminf(v, __shfl_xor(v, 16, 64));
        if (lo == 0) {
            int rr = (r & 3) + ((r >> 2) << 3) + (hi << 2);
            atomicMin((int*)&rowMin[rw + rr], __float_as_int(fmaxf(v, 0.f)));
        }
    }

    // colmin: merge the 4 wave slices, one global atomicMin per col
    __syncthreads();
    #pragma unroll
    for (int c = 0; c < 2048; c += 256) {
        int cc = c + tid;
        float m = fminf(fminf(cmin[0][cc], cmin[1][cc]),
                        fminf(cmin[2][cc], cmin[3][cc]));
        atomicMin((int*)&colMin[c0 + cc], __float_as_int(m));
    }
}

// ---------------- fused final reduction (one kernel, fixed tree) -----------
__global__ __launch_bounds__(1024) void chamfer_reduce(
    const float* __restrict__ minbuf, float* __restrict__ out)
{
    int tid = threadIdx.x;
    double s = 0.0;
    #pragma unroll
    for (int q = 0; q < 16; ++q) {      // 16 float4 per thread, fixed order
        float4 v = *reinterpret_cast<const float4*>(minbuf + (q * 1024 + tid) * 4);
        s += ((double)v.x + (double)v.y) + ((double)v.z + (double)v.w);
    }
    #pragma unroll
    for (int off = 32; off > 0; off >>= 1) s += __shfl_down(s, off, 64);
    __shared__ double sd[16];
    if ((tid & 63) == 0) sd[tid >> 6] = s;
    __syncthreads();
    if (tid == 0) {
        double t = 0.0;
        #pragma unroll
        for (int w = 0; w < 16; ++w) t += sd[w];
        out[0] = (float)(t / (double)(BATCHES * NPTS));
    }
}

extern "C" void kernel_launch(void* const* d_in, const int* in_sizes, int n_in,
                              void* d_out, int out_size, void* d_ws, size_t ws_size,
                              hipStream_t stream)
{
    const float* x = (const float*)d_in[0];
    const float* y = (const float*)d_in[1];
    float* out = (float*)d_out;

    // ws layout (~2.3 MB):
    float*    minall = (float*)d_ws;                       // 65536 f = 256 KB
    _Float16* pA = (_Float16*)(minall + 65536);            // 1 MB
    _Float16* pB = pA + (size_t)BATCHES * NPTS * 16;       // 1 MB

    chamfer_prep<<<BATCHES * NPTS / 256, 256, 0, stream>>>(x, y, pA, pB,
                                                           (int*)minall);
    chamfer_mfma<<<1024, 256, 0, stream>>>(pA, pB, minall);
    chamfer_reduce<<<1, 1024, 0, stream>>>(minall, out);
}